// Round 4
// baseline (37.401 us; speedup 1.0000x reference)
//
#include <hip/hip_runtime.h>
#include <hip/hip_bf16.h>

// RGCN layer (R=8, B=4, N=1024, I=O=64, NB=4) on MI355X.
//
// Slot folding: out[o] = relu(bias[o] + sum_{j=9o..9o+8} concat[j]).
// Channel c of relation r contributes to o=(64r+c)/9 -> slot s=(r+c)/9 in [0,8).
// aggX[b][n][72]: relation r slot s at 8r+s = o+r, self at 64+s = o+8.
//
//  prep_kernel : 288 blocks (256 relation blocks + 32 self blocks, balanced);
//                w~ fold; x~T[rb][16][1024] bf16 via MFMA (vector stores via
//                LDS bounce); self blocks -> aggX[b][n][64+s]; zeroes deg.
//  agg_kernel  : 512 blocks x 256 thr (2/CU). 32-row K-steps, depth-4 static
//                reg prefetch, raw s_barrier + lgkm fence (loads in flight
//                across barriers), deg reduce spread over all 4 waves.
//                bid remap pairs r-even/r-odd on the same XCD (aggX lines).
//  out_kernel  : out[o] = relu(bias + aggX[o+r1]/deg + [r2!=r1] aggX[o+r2]/deg).

#define NN 1024
#define EPSK 1e-7f

typedef __bf16 bf16x8 __attribute__((ext_vector_type(8)));
typedef float f32x4 __attribute__((ext_vector_type(4)));

__device__ __forceinline__ unsigned short f2bf(float f) {
  union { float f; unsigned int u; } v; v.f = f;
  return (unsigned short)((v.u + 0x7FFFu + ((v.u >> 16) & 1u)) >> 16);
}

// ---------------------------------------------------------------------------
// prep: 288 blocks x 256 thr. bid<256: (r,b,chunk) -> x~T. bid>=256: self only.
// ---------------------------------------------------------------------------
__global__ __launch_bounds__(256) void prep_kernel(
    const float* __restrict__ feat,    // [4,1024,64]
    const float* __restrict__ weight,  // [4,64,64]
    const float* __restrict__ Wo,      // [64,64]
    const float* __restrict__ wcmp,    // [8,4]
    unsigned short* __restrict__ xT,   // [32][16][1024] bf16 (slots 8..15 = 0)
    float* __restrict__ aggX,          // [4][1024][72] f32
    float* __restrict__ deg)           // [32][1024] f32
{
  __shared__ __align__(16) unsigned short featL[128 * 72];  // [n][i] bf16
  __shared__ __align__(16) float wTf[64 * 65];              // [c][i] f32
  __shared__ __align__(16) unsigned short wfold[16 * 72];   // [s][i] bf16
  __shared__ __align__(16) unsigned short stg[16 * 136];    // [s][n] bounce

  const int bid = blockIdx.x;
  const int t = threadIdx.x;
  const bool isSelf = bid >= 256;
  int r, b, chunk;
  if (!isSelf) { r = bid >> 5; b = (bid >> 3) & 3; chunk = bid & 7; }
  else { const int s2 = bid - 256; b = s2 >> 3; chunk = s2 & 7; r = 8; }
  const int n0 = chunk << 7;

  // zero deg (stream-ordered before agg)
  if (bid < 32) {
    for (int k = t; k < NN; k += 256) deg[bid * NN + k] = 0.0f;
  }

  // stage features chunk [128 n][64 i] -> bf16 LDS
  const float* fsrc = feat + ((size_t)(b * NN + n0)) * 64;
  #pragma unroll
  for (int p = 0; p < 8; ++p) {
    const int idx = p * 256 + t;
    const int row = idx >> 4, c4 = idx & 15;
    const float4 v = *reinterpret_cast<const float4*>(fsrc + row * 64 + c4 * 4);
    ushort4 u;
    u.x = f2bf(v.x); u.y = f2bf(v.y); u.z = f2bf(v.z); u.w = f2bf(v.w);
    *reinterpret_cast<ushort4*>(&featL[row * 72 + c4 * 4]) = u;
  }

  // wTf[c][i] = w_full[i][c] (relation) or Wo[i][c] (self)
  if (!isSelf) {
    const float wc0 = wcmp[r * 4 + 0], wc1 = wcmp[r * 4 + 1];
    const float wc2 = wcmp[r * 4 + 2], wc3 = wcmp[r * 4 + 3];
    #pragma unroll
    for (int jj = 0; jj < 16; ++jj) {
      const int e = jj * 256 + t;
      const int i = e >> 6, c = e & 63;
      wTf[c * 65 + i] = wc0 * weight[i * 64 + c] + wc1 * weight[4096 + i * 64 + c] +
                        wc2 * weight[8192 + i * 64 + c] + wc3 * weight[12288 + i * 64 + c];
    }
  } else {
    #pragma unroll
    for (int jj = 0; jj < 16; ++jj) {
      const int e = jj * 256 + t;
      const int i = e >> 6, c = e & 63;
      wTf[c * 65 + i] = Wo[i * 64 + c];
    }
  }
  __syncthreads();

  // fold: wfold[s][i] = sum_{c : (r+c)/9 == s} wTf[c][i]; rows 8..15 zero
  #pragma unroll
  for (int jj = 0; jj < 4; ++jj) {
    const int e = jj * 256 + t;
    const int s = e >> 6, i = e & 63;
    float sum = 0.f;
    if (s < 8) {
      const int c0 = 9 * s - r;
      const int clo = c0 < 0 ? 0 : c0;
      const int chi = (c0 + 8 > 63) ? 63 : c0 + 8;
      for (int c = clo; c <= chi; ++c) sum += wTf[c * 65 + i];
    }
    wfold[s * 72 + i] = f2bf(sum);
  }
  __syncthreads();

  const int w = t >> 6, lane = t & 63;
  const int li = lane & 15, lg = lane >> 4;

  // MFMA: D[slot][n] = sum_i wfold[slot][i] * featL[n][i]
  f32x4 acc0 = {0.f, 0.f, 0.f, 0.f}, acc1 = {0.f, 0.f, 0.f, 0.f};
  #pragma unroll
  for (int ks = 0; ks < 2; ++ks) {
    const int kof = ks * 32 + lg * 8;
    const bf16x8 af = __builtin_bit_cast(bf16x8,
        *reinterpret_cast<const uint4*>(&wfold[li * 72 + kof]));
    const bf16x8 b0 = __builtin_bit_cast(bf16x8,
        *reinterpret_cast<const uint4*>(&featL[((2 * w + 0) * 16 + li) * 72 + kof]));
    const bf16x8 b1 = __builtin_bit_cast(bf16x8,
        *reinterpret_cast<const uint4*>(&featL[((2 * w + 1) * 16 + li) * 72 + kof]));
    acc0 = __builtin_amdgcn_mfma_f32_16x16x32_bf16(af, b0, acc0, 0, 0, 0);
    acc1 = __builtin_amdgcn_mfma_f32_16x16x32_bf16(af, b1, acc1, 0, 0, 0);
  }

  if (!isSelf) {
    // bounce D[slot = lg*4+qq][n = tile*16+li] into stg, then vector store
    #pragma unroll
    for (int qq = 0; qq < 4; ++qq) {
      const int s = lg * 4 + qq;
      stg[s * 136 + (2 * w + 0) * 16 + li] = f2bf(acc0[qq]);
      stg[s * 136 + (2 * w + 1) * 16 + li] = f2bf(acc1[qq]);
    }
    __syncthreads();
    const int slot = t >> 4, seg = t & 15;
    *reinterpret_cast<uint4*>(xT + ((size_t)(r * 4 + b) << 14) + slot * NN + n0 + seg * 8) =
        *reinterpret_cast<const uint4*>(&stg[slot * 136 + seg * 8]);
  } else {
    #pragma unroll
    for (int qq = 0; qq < 4; ++qq) {
      const int s = lg * 4 + qq;
      if (s < 8) {
        aggX[((size_t)(b * NN + n0 + (2 * w + 0) * 16 + li)) * 72 + 64 + s] = acc0[qq];
        aggX[((size_t)(b * NN + n0 + (2 * w + 1) * 16 + li)) * 72 + 64 + s] = acc1[qq];
      }
    }
  }
}

// ---------------------------------------------------------------------------
// agg: 512 blocks x 256 thr (2 blocks/CU). 32-row steps, depth-4 prefetch.
// ---------------------------------------------------------------------------
#define AGG_STEP(U, S)                                                            \
  {                                                                               \
    const int s_ = (S);                                                           \
    const int buf_ = s_ & 1;                                                      \
    unsigned short* at_ = &adjT[buf_][0];                                         \
    const int a0_[4] = {pA[U].x, pA[U].y, pA[U].z, pA[U].w};                      \
    const int a1_[4] = {pB[U].x, pB[U].y, pB[U].z, pB[U].w};                      \
    _Pragma("unroll")                                                             \
    for (int jj = 0; jj < 4; ++jj) {                                              \
      const int row_ = (q << 2) + jj;                                             \
      const int col_ = (mp << 1) ^ (((row_ >> 4) & 3) << 3);                      \
      const unsigned int packed_ =                                                \
          (a0_[jj] ? 0x3F80u : 0u) | (a1_[jj] ? 0x3F800000u : 0u);                \
      *reinterpret_cast<unsigned int*>(&at_[row_ * 40 + col_]) = packed_;         \
    }                                                                             \
    degP[buf_][2 * mp][q]     = (float)(a0_[0] + a0_[1] + a0_[2] + a0_[3]);       \
    degP[buf_][2 * mp + 1][q] = (float)(a1_[0] + a1_[1] + a1_[2] + a1_[3]);       \
    if (s_ < 28) {                                                                \
      const int* ns_ = asrc + ((size_t)((s_ + 4) * 32) << 10);                    \
      pA[U] = *reinterpret_cast<const int4*>(ns_ + ((size_t)(2 * mp) << 10));     \
      pB[U] = *reinterpret_cast<const int4*>(ns_ + ((size_t)(2 * mp + 1) << 10)); \
    }                                                                             \
    asm volatile("s_waitcnt lgkmcnt(0)" ::: "memory");                            \
    __builtin_amdgcn_s_barrier();                                                 \
    {                                                                             \
      const int row_ = t >> 3, j_ = t & 7;                                        \
      const float2 d2_ =                                                          \
          *reinterpret_cast<const float2*>(&degP[buf_][row_][2 * j_]);            \
      float sum_ = d2_.x + d2_.y;                                                 \
      sum_ += __shfl_xor(sum_, 1, 64);                                            \
      sum_ += __shfl_xor(sum_, 2, 64);                                            \
      sum_ += __shfl_xor(sum_, 4, 64);                                            \
      if (j_ == 0) atomicAdd(&deg[rb * NN + s_ * 32 + row_], sum_);               \
    }                                                                             \
    const bf16x8 af_ = __builtin_bit_cast(bf16x8,                                 \
        *reinterpret_cast<const uint4*>(&at_[aoffs]));                            \
    const bf16x8 bv_ = __builtin_bit_cast(bf16x8,                                 \
        *reinterpret_cast<const uint4*>(&xlds[boffs + s_ * 32]));                 \
    acc = __builtin_amdgcn_mfma_f32_16x16x32_bf16(af_, bv_, acc, 0, 0, 0);        \
  }

__global__ __launch_bounds__(256) void agg_kernel(
    const int* __restrict__ adj,            // [32][1024][1024]
    const unsigned short* __restrict__ xT,  // [32][16][1024] bf16
    float* __restrict__ aggX,               // [4][1024][72]
    float* __restrict__ deg)                // [32][1024]
{
  __shared__ __align__(16) unsigned short xlds[16 * 1032];   // [slot][m] bf16
  __shared__ __align__(16) unsigned short adjT[2][64 * 40];  // [n][m^swz] bf16
  __shared__ __align__(16) float degP[2][32][20];            // deg partials

  // bid remap: r-even/r-odd siblings (same b, panel) are 256 apart -> same XCD
  const int bid = blockIdx.x;
  const int qq2 = bid & 255, hi = bid >> 8;
  const int r = ((qq2 & 3) << 1) | hi;
  const int b = (qq2 >> 2) & 3;
  const int rb = r * 4 + b;
  const int ncol0 = (qq2 >> 4) << 6;
  const int t = threadIdx.x;
  const int q = t & 15, mp = t >> 4;  // column-quad, row-pair

  const int* asrc = adj + (((size_t)rb) << 20) + ncol0 + (q << 2);

  // issue prefetch for steps 0..3 first (oldest in vmcnt queue)
  int4 pA[4], pB[4];
  #pragma unroll
  for (int u = 0; u < 4; ++u) {
    pA[u] = *reinterpret_cast<const int4*>(asrc + ((size_t)(u * 32 + 2 * mp) << 10));
    pB[u] = *reinterpret_cast<const int4*>(asrc + ((size_t)(u * 32 + 2 * mp + 1) << 10));
  }

  // stage x~ panel (32 KB) into LDS
  const unsigned short* xs = xT + (((size_t)rb) << 14);
  #pragma unroll
  for (int it = 0; it < 8; ++it) {
    const int idx = t + (it << 8);
    const int row = idx >> 7, seg = idx & 127;
    *reinterpret_cast<uint4*>(&xlds[row * 1032 + seg * 8]) =
        *reinterpret_cast<const uint4*>(xs + row * NN + seg * 8);
  }

  const int w = t >> 6, lane = t & 63;
  const int li = lane & 15, lg = lane >> 4;
  const int arow = w * 16 + li;
  const int aoffs = arow * 40 + ((lg * 8) ^ ((w & 3) << 3));
  const int boffs = li * 1032 + lg * 8;

  f32x4 acc = {0.f, 0.f, 0.f, 0.f};

  __syncthreads();  // xlds ready

  for (int tt = 0; tt < 8; ++tt) {
    AGG_STEP(0, 4 * tt + 0);
    AGG_STEP(1, 4 * tt + 1);
    AGG_STEP(2, 4 * tt + 2);
    AGG_STEP(3, 4 * tt + 3);
  }

  // lane holds D[n = w*16 + lg*4 + qq][slot = li] (slots 0..7 valid)
  float* dst = aggX + ((size_t)(b * NN + ncol0)) * 72 + r * 8;
  if (li < 8) {
    #pragma unroll
    for (int qq = 0; qq < 4; ++qq) {
      const int n = w * 16 + lg * 4 + qq;
      dst[(size_t)n * 72 + li] = acc[qq];
    }
  }
}

// ---------------------------------------------------------------------------
// epilogue
// ---------------------------------------------------------------------------
__global__ __launch_bounds__(256) void out_kernel(
    const float* __restrict__ aggX, const float* __restrict__ deg,
    const float* __restrict__ bias, float* __restrict__ out)
{
  const int gid = blockIdx.x * 256 + threadIdx.x;
  const int o = gid & 63;
  const int n = (gid >> 6) & 1023;
  const int b = gid >> 16;
  const float* cp = aggX + ((size_t)(b * NN + n)) * 72;

  const int r1 = (9 * o) >> 6;
  const int r2 = (9 * o + 8) >> 6;

  float v1 = cp[o + r1];
  if (r1 < 8) v1 /= (deg[(r1 * 4 + b) * NN + n] + EPSK);
  float acc = bias[o] + v1;
  if (r2 != r1) {
    float v2 = cp[o + r2];
    if (r2 < 8) v2 /= (deg[(r2 * 4 + b) * NN + n] + EPSK);
    acc += v2;
  }
  out[gid] = fmaxf(acc, 0.0f);
}

extern "C" void kernel_launch(void* const* d_in, const int* in_sizes, int n_in,
                              void* d_out, int out_size, void* d_ws, size_t ws_size,
                              hipStream_t stream) {
  const float* feat   = (const float*)d_in[0];
  const int*   adj    = (const int*)d_in[1];
  const float* weight = (const float*)d_in[2];
  const float* Wo     = (const float*)d_in[3];
  const float* wcmp   = (const float*)d_in[4];
  const float* bias   = (const float*)d_in[5];
  float* out = (float*)d_out;

  // ws layout: x~T (1 MiB bf16) | aggX (1.125 MiB f32) | deg (128 KiB f32)
  char* ws = (char*)d_ws;
  unsigned short* xT = (unsigned short*)(ws);
  float* aggX = (float*)(ws + 1048576u);
  float* deg  = (float*)(ws + 1048576u + 1179648u);

  prep_kernel<<<dim3(288), dim3(256), 0, stream>>>(feat, weight, Wo, wcmp, xT, aggX, deg);
  agg_kernel<<<dim3(512), dim3(256), 0, stream>>>(adj, xT, aggX, deg);
  out_kernel<<<dim3(1024), dim3(256), 0, stream>>>(aggX, deg, bias, out);
}

// Round 5
// 35.241 us; speedup vs baseline: 1.0613x; 1.0613x over previous
//
#include <hip/hip_runtime.h>
#include <hip/hip_bf16.h>

// RGCN layer (R=8, B=4, N=1024, I=O=64, NB=4) on MI355X.
//
// Slot folding: out[o] = relu(bias[o] + sum_{j=9o..9o+8} concat[j]).
// Channel c of relation r contributes to o=(64r+c)/9 -> slot s=(r+c)/9 in [0,8).
// Per-relation folded weights w~[i][s] (8 slots). Slot read-back: s = o - 7r.
//
//  prep_kernel : 288 blocks; w~ fold; x~[rb][n][8] f32 via MFMA (bf16 in, f32
//                out, coalesced via LDS bounce); self blocks -> selfP[b][n][8];
//                zeroes deg.
//  agg_kernel  : 512 blocks x 256 thr (2/CU), VALU streaming — NO main-loop
//                barriers, no transpose, no MFMA. Block=(rb, n-quarter 256,
//                m-quarter 256). Thread (tm,tn): int4 adj loads (contiguous
//                1KB/row-group), 32 v_fmac into acc[4n][8s]; deg partial via
//                1 ds_write/m + end reduce (exact int-in-f32 atomics).
//                Partials -> aggP[mq][rb][n][8] (non-atomic, deterministic).
//  out_kernel  : out[o] = relu(bias + sum_mq term(r1) + [r2!=r1] sum_mq term(r2)),
//                term(r) = aggP[.]/(deg+eps), r==8 -> selfP.

#define NN 1024
#define EPSK 1e-7f

typedef __bf16 bf16x8 __attribute__((ext_vector_type(8)));
typedef float f32x4 __attribute__((ext_vector_type(4)));

__device__ __forceinline__ unsigned short f2bf(float f) {
  union { float f; unsigned int u; } v; v.f = f;
  return (unsigned short)((v.u + 0x7FFFu + ((v.u >> 16) & 1u)) >> 16);
}

// ---------------------------------------------------------------------------
// prep: 288 blocks x 256 thr. bid<256: (r,b,chunk) -> x~ f32. bid>=256: self.
// ---------------------------------------------------------------------------
__global__ __launch_bounds__(256) void prep_kernel(
    const float* __restrict__ feat,    // [4,1024,64]
    const float* __restrict__ weight,  // [4,64,64]
    const float* __restrict__ Wo,      // [64,64]
    const float* __restrict__ wcmp,    // [8,4]
    float* __restrict__ xf,            // [32][1024][8] f32
    float* __restrict__ selfP,         // [4][1024][8] f32
    float* __restrict__ deg)           // [32][1024] f32
{
  __shared__ __align__(16) unsigned short featL[128 * 72];  // [n][i] bf16
  __shared__ __align__(16) float wTf[64 * 65];              // [c][i] f32
  __shared__ __align__(16) unsigned short wfold[16 * 72];   // [s][i] bf16
  __shared__ __align__(16) float stg[128 * 8];              // [n][s] f32 bounce

  const int bid = blockIdx.x;
  const int t = threadIdx.x;
  const bool isSelf = bid >= 256;
  int r, b, chunk;
  if (!isSelf) { r = bid >> 5; b = (bid >> 3) & 3; chunk = bid & 7; }
  else { const int s2 = bid - 256; b = s2 >> 3; chunk = s2 & 7; r = 8; }
  const int n0 = chunk << 7;

  // zero deg (stream-ordered before agg)
  if (bid < 32) {
    for (int k = t; k < NN; k += 256) deg[bid * NN + k] = 0.0f;
  }

  // stage features chunk [128 n][64 i] -> bf16 LDS
  const float* fsrc = feat + ((size_t)(b * NN + n0)) * 64;
  #pragma unroll
  for (int p = 0; p < 8; ++p) {
    const int idx = p * 256 + t;
    const int row = idx >> 4, c4 = idx & 15;
    const float4 v = *reinterpret_cast<const float4*>(fsrc + row * 64 + c4 * 4);
    ushort4 u;
    u.x = f2bf(v.x); u.y = f2bf(v.y); u.z = f2bf(v.z); u.w = f2bf(v.w);
    *reinterpret_cast<ushort4*>(&featL[row * 72 + c4 * 4]) = u;
  }

  // wTf[c][i] = w_full[i][c] (relation) or Wo[i][c] (self)
  if (!isSelf) {
    const float wc0 = wcmp[r * 4 + 0], wc1 = wcmp[r * 4 + 1];
    const float wc2 = wcmp[r * 4 + 2], wc3 = wcmp[r * 4 + 3];
    #pragma unroll
    for (int jj = 0; jj < 16; ++jj) {
      const int e = jj * 256 + t;
      const int i = e >> 6, c = e & 63;
      wTf[c * 65 + i] = wc0 * weight[i * 64 + c] + wc1 * weight[4096 + i * 64 + c] +
                        wc2 * weight[8192 + i * 64 + c] + wc3 * weight[12288 + i * 64 + c];
    }
  } else {
    #pragma unroll
    for (int jj = 0; jj < 16; ++jj) {
      const int e = jj * 256 + t;
      const int i = e >> 6, c = e & 63;
      wTf[c * 65 + i] = Wo[i * 64 + c];
    }
  }
  __syncthreads();

  // fold: wfold[s][i] = sum_{c : (r+c)/9 == s} wTf[c][i]; rows 8..15 zero
  #pragma unroll
  for (int jj = 0; jj < 4; ++jj) {
    const int e = jj * 256 + t;
    const int s = e >> 6, i = e & 63;
    float sum = 0.f;
    if (s < 8) {
      const int c0 = 9 * s - r;
      const int clo = c0 < 0 ? 0 : c0;
      const int chi = (c0 + 8 > 63) ? 63 : c0 + 8;
      for (int c = clo; c <= chi; ++c) sum += wTf[c * 65 + i];
    }
    wfold[s * 72 + i] = f2bf(sum);
  }
  __syncthreads();

  const int w = t >> 6, lane = t & 63;
  const int li = lane & 15, lg = lane >> 4;

  // MFMA: D[slot][n] = sum_i wfold[slot][i] * featL[n][i]
  f32x4 acc0 = {0.f, 0.f, 0.f, 0.f}, acc1 = {0.f, 0.f, 0.f, 0.f};
  #pragma unroll
  for (int ks = 0; ks < 2; ++ks) {
    const int kof = ks * 32 + lg * 8;
    const bf16x8 af = __builtin_bit_cast(bf16x8,
        *reinterpret_cast<const uint4*>(&wfold[li * 72 + kof]));
    const bf16x8 b0 = __builtin_bit_cast(bf16x8,
        *reinterpret_cast<const uint4*>(&featL[((2 * w + 0) * 16 + li) * 72 + kof]));
    const bf16x8 b1 = __builtin_bit_cast(bf16x8,
        *reinterpret_cast<const uint4*>(&featL[((2 * w + 1) * 16 + li) * 72 + kof]));
    acc0 = __builtin_amdgcn_mfma_f32_16x16x32_bf16(af, b0, acc0, 0, 0, 0);
    acc1 = __builtin_amdgcn_mfma_f32_16x16x32_bf16(af, b1, acc1, 0, 0, 0);
  }

  // lane holds D[slot=lg*4+qq][n=tile*16+li]; slots >=8 are zero -> drop
  if (lg < 2) {
    #pragma unroll
    for (int qq = 0; qq < 4; ++qq) {
      const int s = lg * 4 + qq;
      stg[((2 * w + 0) * 16 + li) * 8 + s] = acc0[qq];
      stg[((2 * w + 1) * 16 + li) * 8 + s] = acc1[qq];
    }
  }
  __syncthreads();
  // coalesced copy: 4 KB = 256 thr x 16 B
  {
    float* dstF = isSelf ? (selfP + ((size_t)(b * NN + n0)) * 8)
                         : (xf + ((size_t)((r * 4 + b) * NN + n0)) * 8);
    *reinterpret_cast<float4*>(dstF + t * 4) =
        *reinterpret_cast<const float4*>(&stg[t * 4]);
  }
}

// ---------------------------------------------------------------------------
// agg: 512 blocks x 256 thr (2/CU). Block=(rb, nq, mq). Pure VALU streaming.
// ---------------------------------------------------------------------------
__global__ __launch_bounds__(256) void agg_kernel(
    const int* __restrict__ adj,    // [32][1024][1024]
    const float* __restrict__ xf,   // [32][1024][8] f32
    float* __restrict__ aggP,       // [4 mq][32 rb][1024 n][8 s] f32
    float* __restrict__ deg)        // [32][1024] f32
{
  __shared__ __align__(16) float xsL[256 * 8];    // x~ panel (m-quarter), 8 KB
  __shared__ __align__(16) float degL[256 * 66];  // deg partials; tail reused

  const int bid = blockIdx.x;
  const int rb = bid >> 4, mq = (bid >> 2) & 3, nq = bid & 3;
  const int t = threadIdx.x;
  const int tm = t >> 6, tn = t & 63;  // wave index = m-phase; lane = n-quad
  const int mbase = mq << 8, nbase = nq << 8;

  // stage x~ panel: 8 KB contiguous
  {
    const float* xs = xf + ((size_t)(rb * NN + mbase)) * 8;
    *reinterpret_cast<float4*>(&xsL[t * 8]) = *reinterpret_cast<const float4*>(xs + t * 8);
    *reinterpret_cast<float4*>(&xsL[t * 8 + 4]) = *reinterpret_cast<const float4*>(xs + t * 8 + 4);
  }

  const int* asrc = adj + (((size_t)rb) << 20) + ((size_t)mbase << 10) + nbase + (tn << 2);

  float acc[4][8];
  #pragma unroll
  for (int j = 0; j < 4; ++j)
    #pragma unroll
    for (int s = 0; s < 8; ++s) acc[j][s] = 0.f;

  __syncthreads();  // xsL ready

  // m-loop: i=0..63, m_local = 4i + tm (rolling contiguous 4-row window/block)
  int4 buf0 = *reinterpret_cast<const int4*>(asrc + ((size_t)(0 * 4 + tm) << 10));
  int4 buf1 = *reinterpret_cast<const int4*>(asrc + ((size_t)(1 * 4 + tm) << 10));
  int4 buf2 = *reinterpret_cast<const int4*>(asrc + ((size_t)(2 * 4 + tm) << 10));
  int4 buf3 = *reinterpret_cast<const int4*>(asrc + ((size_t)(3 * 4 + tm) << 10));

#define AGG_BODY(BUF, I)                                                        \
  {                                                                             \
    const int4 cur_ = BUF;                                                      \
    const int ml_ = ((I) << 2) + tm;                                            \
    if ((I) < 60) {                                                             \
      BUF = *reinterpret_cast<const int4*>(asrc + ((size_t)(ml_ + 16) << 10));  \
    }                                                                           \
    const float a0_ = (float)cur_.x, a1_ = (float)cur_.y;                       \
    const float a2_ = (float)cur_.z, a3_ = (float)cur_.w;                       \
    degL[ml_ * 66 + tn] = (float)(cur_.x + cur_.y + cur_.z + cur_.w);           \
    const float4 xlo_ = *reinterpret_cast<const float4*>(&xsL[ml_ * 8]);        \
    const float4 xhi_ = *reinterpret_cast<const float4*>(&xsL[ml_ * 8 + 4]);    \
    const float xs_[8] = {xlo_.x, xlo_.y, xlo_.z, xlo_.w,                       \
                          xhi_.x, xhi_.y, xhi_.z, xhi_.w};                      \
    _Pragma("unroll")                                                           \
    for (int s_ = 0; s_ < 8; ++s_) {                                            \
      acc[0][s_] = fmaf(a0_, xs_[s_], acc[0][s_]);                              \
      acc[1][s_] = fmaf(a1_, xs_[s_], acc[1][s_]);                              \
      acc[2][s_] = fmaf(a2_, xs_[s_], acc[2][s_]);                              \
      acc[3][s_] = fmaf(a3_, xs_[s_], acc[3][s_]);                              \
    }                                                                           \
  }

  for (int ib = 0; ib < 16; ++ib) {
    AGG_BODY(buf0, ib * 4 + 0);
    AGG_BODY(buf1, ib * 4 + 1);
    AGG_BODY(buf2, ib * 4 + 2);
    AGG_BODY(buf3, ib * 4 + 3);
  }
#undef AGG_BODY

  __syncthreads();

  // deg reduce: thread t owns m_local=t; sum 64 tn-partials; exact int in f32
  {
    float s = 0.f;
    #pragma unroll
    for (int k = 0; k < 32; ++k) {
      const float2 v = *reinterpret_cast<const float2*>(&degL[t * 66 + 2 * k]);
      s += v.x + v.y;
    }
    atomicAdd(&deg[rb * NN + mbase + t], s);
  }
  __syncthreads();

  // acc reduce across tm via LDS (reuse degL region, stride 36 to spread banks)
  float* accL = degL;
  #pragma unroll
  for (int j = 0; j < 4; ++j) {
    *reinterpret_cast<float4*>(&accL[t * 36 + j * 8]) =
        make_float4(acc[j][0], acc[j][1], acc[j][2], acc[j][3]);
    *reinterpret_cast<float4*>(&accL[t * 36 + j * 8 + 4]) =
        make_float4(acc[j][4], acc[j][5], acc[j][6], acc[j][7]);
  }
  __syncthreads();
  {
    const int nl = t;                 // n_local 0..255
    const int tn2 = nl >> 2, j2 = nl & 3;
    float o8[8];
    #pragma unroll
    for (int s = 0; s < 8; ++s) o8[s] = 0.f;
    #pragma unroll
    for (int tm2 = 0; tm2 < 4; ++tm2) {
      const int base = (tm2 * 64 + tn2) * 36 + j2 * 8;
      const float4 lo = *reinterpret_cast<const float4*>(&accL[base]);
      const float4 hi = *reinterpret_cast<const float4*>(&accL[base + 4]);
      o8[0] += lo.x; o8[1] += lo.y; o8[2] += lo.z; o8[3] += lo.w;
      o8[4] += hi.x; o8[5] += hi.y; o8[6] += hi.z; o8[7] += hi.w;
    }
    float* dst = aggP + (((size_t)(mq * 32 + rb)) * NN + nbase + nl) * 8;
    *reinterpret_cast<float4*>(dst) = make_float4(o8[0], o8[1], o8[2], o8[3]);
    *reinterpret_cast<float4*>(dst + 4) = make_float4(o8[4], o8[5], o8[6], o8[7]);
  }
}

// ---------------------------------------------------------------------------
// epilogue: combine 4 mq-partials + self, divide by deg, bias, relu
// ---------------------------------------------------------------------------
__global__ __launch_bounds__(256) void out_kernel(
    const float* __restrict__ aggP,   // [4][32][1024][8]
    const float* __restrict__ selfP,  // [4][1024][8]
    const float* __restrict__ deg,    // [32][1024]
    const float* __restrict__ bias, float* __restrict__ out)
{
  const int gid = blockIdx.x * 256 + threadIdx.x;
  const int o = gid & 63;
  const int n = (gid >> 6) & 1023;
  const int b = gid >> 16;

  const int r1 = (9 * o) >> 6;
  const int r2 = (9 * o + 8) >> 6;

  float acc = bias[o];
  #pragma unroll
  for (int pass = 0; pass < 2; ++pass) {
    const int r = pass ? r2 : r1;
    if (pass && r2 == r1) break;
    const int s = o - 7 * r;
    float v;
    if (r < 8) {
      const size_t base = (((size_t)(r * 4 + b)) * NN + n) * 8 + s;
      v = aggP[base] + aggP[base + 262144] + aggP[base + 524288] + aggP[base + 786432];
      v /= (deg[(r * 4 + b) * NN + n] + EPSK);
    } else {
      v = selfP[((size_t)(b * NN + n)) * 8 + (o - 56)];
    }
    acc += v;
  }
  out[gid] = fmaxf(acc, 0.0f);
}

extern "C" void kernel_launch(void* const* d_in, const int* in_sizes, int n_in,
                              void* d_out, int out_size, void* d_ws, size_t ws_size,
                              hipStream_t stream) {
  const float* feat   = (const float*)d_in[0];
  const int*   adj    = (const int*)d_in[1];
  const float* weight = (const float*)d_in[2];
  const float* Wo     = (const float*)d_in[3];
  const float* wcmp   = (const float*)d_in[4];
  const float* bias   = (const float*)d_in[5];
  float* out = (float*)d_out;

  // ws: x~ f32 (1 MiB) | selfP (128 KiB) | aggP (4 MiB) | deg (128 KiB)
  char* ws = (char*)d_ws;
  float* xf    = (float*)(ws);
  float* selfP = (float*)(ws + 1048576u);
  float* aggP  = (float*)(ws + 1048576u + 131072u);
  float* deg   = (float*)(ws + 1048576u + 131072u + 4194304u);

  prep_kernel<<<dim3(288), dim3(256), 0, stream>>>(feat, weight, Wo, wcmp, xf, selfP, deg);
  agg_kernel<<<dim3(512), dim3(256), 0, stream>>>(adj, xf, aggP, deg);
  out_kernel<<<dim3(1024), dim3(256), 0, stream>>>(aggP, selfP, deg, bias, out);
}